// Round 9
// baseline (626.194 us; speedup 1.0000x reference)
//
#include <hip/hip_runtime.h>
#include <math.h>

#define N 8192
#define NW 128          // 64-bit mask words per row
#define FIN 29
#define FH 8
#define NH 4
#define ALPHA 0.2f
#define LOG2E 1.4426950408889634f

typedef unsigned long long ull;

__device__ inline unsigned bf16rn(float f) {
    unsigned u = __float_as_uint(f);
    return (u + 0x7fffu + ((u >> 16) & 1u)) >> 16;
}
// unpack a uint32 holding two bf16 -> float2 {lo, hi}
__device__ inline float2 bfpair(unsigned u) {
    return make_float2(__uint_as_float(u << 16), __uint_as_float(u & 0xffff0000u));
}
// monotone float <-> unsigned encoding for atomicMax
__device__ inline unsigned fenc(float x) {
    unsigned u = __float_as_uint(x);
    return (u & 0x80000000u) ? ~u : (u | 0x80000000u);
}
__device__ inline float fdec(unsigned e) {
    return __uint_as_float((e & 0x80000000u) ? (e & 0x7fffffffu) : ~e);
}
// w if this lane's bit of wave-uniform mw is set, else 0.
// readfirstlane forces the word into SGPRs so the "s" constraint is satisfiable;
// v_cndmask_b32 with an SGPR-pair mask does the lane-indexed bit select in 1 VALU op.
__device__ inline float selmask(float w, ull mw) {
    unsigned lo = __builtin_amdgcn_readfirstlane((unsigned)mw);
    unsigned hi = __builtin_amdgcn_readfirstlane((unsigned)(mw >> 32));
    ull smw = ((ull)hi << 32) | lo;
    float r;
    asm("v_cndmask_b32 %0, 0, %1, %2" : "=v"(r) : "v"(w), "s"(smw));
    return r;
}

// ---------------- K0: pack adj (256 MB int32) into bitmask (8 MB) ----------------
__global__ void k0_pack(const int* __restrict__ adj, ull* __restrict__ mask,
                        unsigned* __restrict__ amax) {
    int row = blockIdx.x;
    int tid = threadIdx.x;
    int lane = tid & 63;
    int wave = tid >> 6;
    if (row == 0 && tid < 8) amax[tid] = 0u;   // init atomic-max slots (k1 runs next)
    const int* rp = adj + (size_t)row * N;
#pragma unroll 8
    for (int i = 0; i < 32; i++) {
        int a = rp[i * 256 + tid];
        ull b = __ballot(a > 0);
        if (lane == 0) mask[(size_t)row * NW + i * 4 + wave] = b;
    }
}

// ---------------- K1: per-node features; tuple (f2, E1=2^f2, E2=2^(a*f2)); h bf16 ----------------
__global__ __launch_bounds__(64) void k1_feat(
    const float* __restrict__ x, const float* __restrict__ Wh,
    const float* __restrict__ ah,
    float4* __restrict__ tup1, uint4* __restrict__ hpk,
    float* __restrict__ f1a, unsigned* __restrict__ amax) {
    __shared__ float sW[NH * FIN * FH];
    __shared__ float sa[NH * 2 * FH];
    int tid = threadIdx.x;
    for (int i = tid; i < NH * FIN * FH; i += 64) sW[i] = Wh[i];
    for (int i = tid; i < NH * 2 * FH; i += 64) sa[i] = ah[i];
    __syncthreads();
    int node = blockIdx.x * 64 + tid;   // N % 64 == 0
    float xr[FIN];
#pragma unroll
    for (int f = 0; f < FIN; f++) xr[f] = x[node * FIN + f];
    float f2v[NH];
#pragma unroll
    for (int h = 0; h < NH; h++) {
        float hv[FH];
#pragma unroll
        for (int k = 0; k < FH; k++) {
            float s = 0.f;
#pragma unroll
            for (int f = 0; f < FIN; f++) s += xr[f] * sW[(h * FIN + f) * FH + k];
            hv[k] = s;
        }
        float f1 = 0.f, f2 = 0.f;
#pragma unroll
        for (int k = 0; k < FH; k++) {
            f1 += hv[k] * sa[h * 16 + k];
            f2 += hv[k] * sa[h * 16 + 8 + k];
        }
        float f2s = f2 * LOG2E;
        f2v[h] = f2s;
        tup1[h * N + node] = make_float4(f2s,
                                         __builtin_amdgcn_exp2f(f2s),
                                         __builtin_amdgcn_exp2f(ALPHA * f2s), 0.f);
        f1a[node * 4 + h] = f1 * LOG2E;
        uint4 p;
        p.x = (bf16rn(hv[1]) << 16) | bf16rn(hv[0]);
        p.y = (bf16rn(hv[3]) << 16) | bf16rn(hv[2]);
        p.z = (bf16rn(hv[5]) << 16) | bf16rn(hv[4]);
        p.w = (bf16rn(hv[7]) << 16) | bf16rn(hv[6]);
        hpk[h * N + node] = p;
    }
#pragma unroll
    for (int h = 0; h < NH; h++) {
        float v = f2v[h];
        for (int off = 32; off > 0; off >>= 1) v = fmaxf(v, __shfl_xor(v, off, 64));
        if (tid == 0) atomicMax(&amax[h], fenc(v));
    }
}

// ---------------- K3: layer-1 attention partials — 1 head/block, 4 rows/wave ----------------
// w = (f1+f2>=0) ? C1*E1 : C2*E2 ; C per-row consts, E per-j from tuple. No inner exp2.
// Live state: 36 accs + 12 consts + ~40 temps ~= 90 VGPR — under the 128-spill tier.
// blockIdx.x = (rowblk * JS1 + js) * NH + h ; grid = (N/32)*JS1*NH = 2048
#define TJ 512
#define JS1 2
__global__ __launch_bounds__(512) void k3_attn1(
    const ull* __restrict__ mask, const float4* __restrict__ tup1,
    const uint4* __restrict__ hpk, const float* __restrict__ f1a,
    const unsigned* __restrict__ amax, float* __restrict__ part1) {
    __shared__ float4 tT[TJ];   // 8 KB
    __shared__ uint4 tH[TJ];    // 8 KB
    int tid = threadIdx.x;
    int lane = tid & 63;
    int wave = tid >> 6;
    int h = blockIdx.x & 3;
    int js = (blockIdx.x >> 2) & (JS1 - 1);
    int rowblk = blockIdx.x >> 3;
    int r0 = rowblk * 32 + wave * 4;
    const int JR = N / JS1;     // 4096
    int jbase = js * JR;

    float mf = fdec(amax[h]);
    float f1r[4], C1[4], C2[4];
#pragma unroll
    for (int r = 0; r < 4; r++) {
        float f1 = f1a[(r0 + r) * 4 + h];
        float v = f1 + mf, m = fmaxf(v, ALPHA * v);
        f1r[r] = f1;
        C1[r] = __builtin_amdgcn_exp2f(f1 - m);
        C2[r] = __builtin_amdgcn_exp2f(ALPHA * f1 - m);
    }
    float2 acc[4][4];
    float dsum[4];
#pragma unroll
    for (int r = 0; r < 4; r++) {
        dsum[r] = 0.f;
#pragma unroll
        for (int k = 0; k < 4; k++) acc[r][k] = make_float2(0.f, 0.f);
    }
    const ull* mr[4];
#pragma unroll
    for (int r = 0; r < 4; r++) mr[r] = mask + (size_t)(r0 + r) * NW;

    for (int t = 0; t < JR / TJ; t++) {   // 8
        __syncthreads();
        int gb = jbase + t * TJ + tid;
        tT[tid] = tup1[h * N + gb];
        tH[tid] = hpk[h * N + gb];
        __syncthreads();
        int wb = (jbase >> 6) + t * (TJ / 64);
#pragma unroll
        for (int s = 0; s < TJ / 64; s++) {   // 8
            ull mw[4];
#pragma unroll
            for (int r = 0; r < 4; r++) mw[r] = mr[r][wb + s];
            int jl = s * 64 + lane;
            float4 tq = tT[jl];    // f2, E1, E2
            uint4 hq = tH[jl];
            float2 hv01 = bfpair(hq.x);
            float2 hv23 = bfpair(hq.y);
            float2 hv45 = bfpair(hq.z);
            float2 hv67 = bfpair(hq.w);
#pragma unroll
            for (int r = 0; r < 4; r++) {
                float sg = f1r[r] + tq.x;
                float E = (sg >= 0.f) ? tq.y : tq.z;
                float C = (sg >= 0.f) ? C1[r] : C2[r];
                float w = selmask(C * E, mw[r]);
                acc[r][0].x = fmaf(w, hv01.x, acc[r][0].x);
                acc[r][0].y = fmaf(w, hv01.y, acc[r][0].y);
                acc[r][1].x = fmaf(w, hv23.x, acc[r][1].x);
                acc[r][1].y = fmaf(w, hv23.y, acc[r][1].y);
                acc[r][2].x = fmaf(w, hv45.x, acc[r][2].x);
                acc[r][2].y = fmaf(w, hv45.y, acc[r][2].y);
                acc[r][3].x = fmaf(w, hv67.x, acc[r][3].x);
                acc[r][3].y = fmaf(w, hv67.y, acc[r][3].y);
                dsum[r] += w;
            }
        }
    }
#pragma unroll
    for (int r = 0; r < 4; r++) {
#pragma unroll
        for (int k = 0; k < 4; k++) {
            for (int off = 32; off > 0; off >>= 1) {
                acc[r][k].x += __shfl_xor(acc[r][k].x, off, 64);
                acc[r][k].y += __shfl_xor(acc[r][k].y, off, 64);
            }
        }
        for (int off = 32; off > 0; off >>= 1)
            dsum[r] += __shfl_xor(dsum[r], off, 64);
    }
    if (lane == 0) {
#pragma unroll
        for (int r = 0; r < 4; r++) {
            int row = r0 + r;
#pragma unroll
            for (int k = 0; k < 4; k++) {
                part1[(js * 36 + h * 9 + 2 * k + 0) * N + row] = acc[r][k].x;
                part1[(js * 36 + h * 9 + 2 * k + 1) * N + row] = acc[r][k].y;
            }
            part1[(js * 36 + h * 9 + 8) * N + row] = dsum[r];
        }
    }
}

// ---------------- K3b: finalize layer 1 + layer-2 features + fused layer-2 max ----------------
__global__ void k3b_final(const float* __restrict__ part1, const float* __restrict__ Wo,
                          const float* __restrict__ ao,
                          float4* __restrict__ rec2, float* __restrict__ f1b,
                          unsigned* __restrict__ amax) {
    __shared__ float sW[64];
    __shared__ float sa[4];
    int tid = threadIdx.x;
    if (tid < 64) sW[tid] = Wo[tid];
    if (tid < 4) sa[tid] = ao[tid];
    __syncthreads();
    int row = blockIdx.x * 256 + tid;
    float hv[32];
#pragma unroll
    for (int h = 0; h < NH; h++) {
        float s[9];
#pragma unroll
        for (int c = 0; c < 9; c++)
            s[c] = part1[(h * 9 + c) * N + row] + part1[(36 + h * 9 + c) * N + row];
        float inv = 1.f / s[8];
#pragma unroll
        for (int k = 0; k < FH; k++) {
            float o = s[k] * inv;
            hv[h * 8 + k] = (o > 0.f) ? o : expm1f(o);
        }
    }
    float h0 = 0.f, h1 = 0.f;
#pragma unroll
    for (int i = 0; i < 32; i++) {
        h0 = fmaf(hv[i], sW[i * 2 + 0], h0);
        h1 = fmaf(hv[i], sW[i * 2 + 1], h1);
    }
    float f1 = (h0 * sa[0] + h1 * sa[1]) * LOG2E;
    float f2 = (h0 * sa[2] + h1 * sa[3]) * LOG2E;
    rec2[row] = make_float4(f2, h0, h1, 0.f);
    f1b[row] = f1;
    float vmax = f2;
    for (int off = 32; off > 0; off >>= 1) vmax = fmaxf(vmax, __shfl_xor(vmax, off, 64));
    if ((tid & 63) == 0) atomicMax(&amax[4], fenc(vmax));
}

// ---------------- K6: layer-2 attention + elu + log_softmax, fully fused ----------------
// Each wave owns 4 complete rows (all 8192 j) -> no partials, no extra kernel.
// rec2 (128 KB) and mask (8 MB) are L2-resident. grid = N/16 = 512, 256 thr.
__global__ __launch_bounds__(256) void k6_attn2(
    const ull* __restrict__ mask, const float4* __restrict__ rec2,
    const float* __restrict__ f1b, const unsigned* __restrict__ amax,
    float* __restrict__ out) {
    int tid = threadIdx.x;
    int lane = tid & 63;
    int wave = tid >> 6;
    int rbase = blockIdx.x * 16 + wave * 4;

    float mb = fdec(amax[4]);
    float f1m[4], f1q[4];
#pragma unroll
    for (int i = 0; i < 4; i++) {
        float f1 = f1b[rbase + i];
        float v = f1 + mb, m = fmaxf(v, ALPHA * v);
        f1m[i] = f1 - m; f1q[i] = ALPHA * f1 - m;
    }
    float a0[4] = {0.f, 0.f, 0.f, 0.f};
    float a1[4] = {0.f, 0.f, 0.f, 0.f};
    float dd[4] = {0.f, 0.f, 0.f, 0.f};
    const ull* mr[4];
#pragma unroll
    for (int i = 0; i < 4; i++) mr[i] = mask + (size_t)(rbase + i) * NW;

#pragma unroll 4
    for (int s = 0; s < N / 64; s++) {   // 128
        float4 q = rec2[s * 64 + lane];
        float p = ALPHA * q.x;
#pragma unroll
        for (int i = 0; i < 4; i++) {
            ull mw = mr[i][s];
            float w = __builtin_amdgcn_exp2f(fmaxf(f1m[i] + q.x, p + f1q[i]));
            w = selmask(w, mw);
            a0[i] = fmaf(w, q.y, a0[i]);
            a1[i] = fmaf(w, q.z, a1[i]);
            dd[i] += w;
        }
    }
#pragma unroll
    for (int i = 0; i < 4; i++) {
        for (int off = 32; off > 0; off >>= 1) {
            a0[i] += __shfl_xor(a0[i], off, 64);
            a1[i] += __shfl_xor(a1[i], off, 64);
            dd[i] += __shfl_xor(dd[i], off, 64);
        }
    }
    if (lane == 0) {
#pragma unroll
        for (int i = 0; i < 4; i++) {
            float inv = 1.f / dd[i];
            float e0 = a0[i] * inv, e1 = a1[i] * inv;
            e0 = (e0 > 0.f) ? e0 : expm1f(e0);
            e1 = (e1 > 0.f) ? e1 : expm1f(e1);
            float mx = fmaxf(e0, e1);
            float lse = mx + logf(expf(e0 - mx) + expf(e1 - mx));
            ((float2*)out)[rbase + i] = make_float2(e0 - lse, e1 - lse);
        }
    }
}

extern "C" void kernel_launch(void* const* d_in, const int* in_sizes, int n_in,
                              void* d_out, int out_size, void* d_ws, size_t ws_size,
                              hipStream_t stream) {
    const float* x   = (const float*)d_in[0];
    const int*   adj = (const int*)d_in[1];
    const float* Wh  = (const float*)d_in[2];
    const float* ah  = (const float*)d_in[3];
    const float* Wo  = (const float*)d_in[4];
    const float* ao  = (const float*)d_in[5];
    float* out = (float*)d_out;
    float* ws = (float*)d_ws;

    // workspace layout (float offsets)
    ull*      mask  = (ull*)ws;                       // 8 MB = 2097152 floats
    float4*   tup1  = (float4*)(ws + 2097152);        // 4*N float4 = 131072 floats
    uint4*    hpk   = (uint4*)(ws + 2228224);         // 4*N uint4  = 131072 floats
    float*    f1a   = ws + 2359296;                   // 4*N
    float*    part1 = ws + 2392064;                   // 2*36*N = 589824
    float4*   rec2  = (float4*)(ws + 2981888);        // N float4
    float*    f1b   = ws + 3014656;                   // N
    unsigned* amax  = (unsigned*)(ws + 3022848);      // 8 slots

    k0_pack<<<N, 256, 0, stream>>>(adj, mask, amax);
    k1_feat<<<N / 64, 64, 0, stream>>>(x, Wh, ah, tup1, hpk, f1a, amax);
    k3_attn1<<<(N / 32) * JS1 * NH, 512, 0, stream>>>(mask, tup1, hpk, f1a, amax, part1);
    k3b_final<<<N / 256, 256, 0, stream>>>(part1, Wo, ao, rec2, f1b, amax);
    k6_attn2<<<N / 16, 256, 0, stream>>>(mask, rec2, f1b, amax, out);
}